// Round 1
// baseline (1122.830 us; speedup 1.0000x reference)
//
#include <hip/hip_runtime.h>
#include <hip/hip_bf16.h>
#include <math.h>

#define B    4
#define T    16384
#define A    256
#define K    256
#define PAD  128
#define TP   (T + 2*PAD)      // 16640 padded length
#define TOUT (TP - K + 1)     // 16385 conv output length
#define ITERS 16
#define NB1  256              // argmax stage-1 blocks per batch

// ---------------- atom normalization: dn[a,k] = d[a,k] / (||d[a]|| + 1e-12)
__global__ void k_norm(const float* __restrict__ d, float* __restrict__ dn) {
    int a = blockIdx.x;
    int k = threadIdx.x;          // 256 threads
    float v = d[a*K + k];
    float s = v*v;
    #pragma unroll
    for (int off = 32; off; off >>= 1) s += __shfl_down(s, off);
    __shared__ float ls[4];
    int lane = threadIdx.x & 63, w = threadIdx.x >> 6;
    if (lane == 0) ls[w] = s;
    __syncthreads();
    if (threadIdx.x == 0) ls[0] = ls[0] + ls[1] + ls[2] + ls[3];
    __syncthreads();
    float norm = sqrtf(ls[0]) + 1e-12f;
    dn[a*K + k] = v / norm;
}

// ---------------- init padded residual + zero recon
__global__ void k_init(const float* __restrict__ x, float* __restrict__ rp,
                       float* __restrict__ recon) {
    int i = blockIdx.x * blockDim.x + threadIdx.x;
    if (i >= B*TP) return;
    int b = i / TP, t = i % TP;
    float v = 0.f;
    if (t >= PAD && t < PAD + T) v = x[b*T + (t - PAD)];
    rp[i] = v;
    recon[i] = 0.f;
}

// ---------------- full cross-correlation: fm[b,a,t] = sum_k rp[b,t+k]*dn[a,k]
__global__ void k_conv_full(const float* __restrict__ rp, const float* __restrict__ dn,
                            float* __restrict__ fm) {
    __shared__ float s_rp[256 + K];   // 512 floats
    __shared__ float s_dn[K];
    int b = blockIdx.z, a = blockIdx.y;
    int t0 = blockIdx.x * 256;
    const float* rpb = rp + b*TP;
    s_dn[threadIdx.x] = dn[a*K + threadIdx.x];
    for (int i = threadIdx.x; i < 256 + K; i += 256) {
        int idx = t0 + i;
        s_rp[i] = (idx < TP) ? rpb[idx] : 0.f;
    }
    __syncthreads();
    int t = t0 + threadIdx.x;
    if (t < TOUT) {
        float acc = 0.f;
        #pragma unroll 8
        for (int k = 0; k < K; k++)
            acc = fmaf(s_rp[threadIdx.x + k], s_dn[k], acc);
        fm[((size_t)b*A + a)*TOUT + t] = acc;
    }
}

// ---------------- incremental recompute of fm window around ctrl.pos (per batch)
__global__ void k_conv_inc(const int* __restrict__ ctrl, const float* __restrict__ rp,
                           const float* __restrict__ dn, float* __restrict__ fm) {
    __shared__ float s_rp[256 + K];
    __shared__ float s_dn[K];
    int b = blockIdx.z, a = blockIdx.y;
    int pos = ctrl[b*4 + 1];
    int tbase = pos - (K - 1) + (int)blockIdx.x * 256;   // window [pos-255, pos+255]
    const float* rpb = rp + b*TP;
    s_dn[threadIdx.x] = dn[a*K + threadIdx.x];
    for (int i = threadIdx.x; i < 256 + K; i += 256) {
        int idx = tbase + i;
        s_rp[i] = (idx >= 0 && idx < TP) ? rpb[idx] : 0.f;
    }
    __syncthreads();
    int t = tbase + threadIdx.x;
    if (t >= 0 && t < TOUT && t <= pos + (K - 1)) {
        float acc = 0.f;
        #pragma unroll 8
        for (int k = 0; k < K; k++)
            acc = fmaf(s_rp[threadIdx.x + k], s_dn[k], acc);
        fm[((size_t)b*A + a)*TOUT + t] = acc;
    }
}

// ---------------- argmax stage 1: per-batch block partials over fm[b]
__global__ void k_amax1(const float* __restrict__ fm, float* __restrict__ pval,
                        int* __restrict__ pidx) {
    int b = blockIdx.y;
    const float* f = fm + (size_t)b*A*TOUT;
    const int n = A*TOUT;
    float best = -INFINITY; int bi = 0x7fffffff;
    for (int i = blockIdx.x*blockDim.x + threadIdx.x; i < n; i += gridDim.x*blockDim.x) {
        float v = f[i];
        if (v > best || (v == best && i < bi)) { best = v; bi = i; }
    }
    #pragma unroll
    for (int off = 32; off; off >>= 1) {
        float ov = __shfl_down(best, off);
        int   oi = __shfl_down(bi, off);
        if (ov > best || (ov == best && oi < bi)) { best = ov; bi = oi; }
    }
    __shared__ float sv[4]; __shared__ int si[4];
    int lane = threadIdx.x & 63, w = threadIdx.x >> 6;
    if (lane == 0) { sv[w] = best; si[w] = bi; }
    __syncthreads();
    if (threadIdx.x == 0) {
        for (int j = 1; j < 4; j++)
            if (sv[j] > best || (sv[j] == best && si[j] < bi)) { best = sv[j]; bi = si[j]; }
        pval[b*NB1 + blockIdx.x] = best;
        pidx[b*NB1 + blockIdx.x] = bi;
    }
}

// ---------------- argmax stage 2: reduce NB1 partials -> ctrl[b] = (atom,pos,val)
__global__ void k_amax2(const float* __restrict__ pval, const int* __restrict__ pidx,
                        int* __restrict__ ctrl) {
    int b = blockIdx.x;
    float best = pval[b*NB1 + threadIdx.x];
    int   bi   = pidx[b*NB1 + threadIdx.x];
    #pragma unroll
    for (int off = 32; off; off >>= 1) {
        float ov = __shfl_down(best, off);
        int   oi = __shfl_down(bi, off);
        if (ov > best || (ov == best && oi < bi)) { best = ov; bi = oi; }
    }
    __shared__ float sv[4]; __shared__ int si[4];
    int lane = threadIdx.x & 63, w = threadIdx.x >> 6;
    if (lane == 0) { sv[w] = best; si[w] = bi; }
    __syncthreads();
    if (threadIdx.x == 0) {
        for (int j = 1; j < 4; j++)
            if (sv[j] > best || (sv[j] == best && si[j] < bi)) { best = sv[j]; bi = si[j]; }
        ctrl[b*4 + 0] = bi / TOUT;                 // atom
        ctrl[b*4 + 1] = bi % TOUT;                 // pos (padded-domain start)
        ((float*)ctrl)[b*4 + 2] = best;            // val
    }
}

// ---------------- apply update: rp -= val*dn[atom] at pos ; recon += same
__global__ void k_update(const int* __restrict__ ctrl, const float* __restrict__ dn,
                         float* __restrict__ rp, float* __restrict__ recon) {
    int b = blockIdx.x;
    int atom = ctrl[b*4 + 0];
    int pos  = ctrl[b*4 + 1];
    float val = ((const float*)ctrl)[b*4 + 2];
    int k = threadIdx.x;                 // K threads
    float av = dn[atom*K + k] * val;
    rp[b*TP + pos + k]    -= av;
    recon[b*TP + pos + k] += av;
}

// ---------------- crop recon padding into output
__global__ void k_out(const float* __restrict__ recon, float* __restrict__ out) {
    int i = blockIdx.x * blockDim.x + threadIdx.x;
    if (i >= B*T) return;
    int b = i / T, t = i % T;
    out[i] = recon[b*TP + PAD + t];
}

extern "C" void kernel_launch(void* const* d_in, const int* in_sizes, int n_in,
                              void* d_out, int out_size, void* d_ws, size_t ws_size,
                              hipStream_t stream) {
    const float* x = (const float*)d_in[0];
    const float* d = (const float*)d_in[1];
    float* out = (float*)d_out;

    float* ws    = (float*)d_ws;
    float* dn    = ws;                          // A*K           = 65536
    float* rp    = dn + (size_t)A*K;            // B*TP          = 66560
    float* recon = rp + (size_t)B*TP;           // B*TP          = 66560
    float* fm    = recon + (size_t)B*TP;        // B*A*TOUT      = 16778240
    float* pval  = fm + (size_t)B*A*TOUT;       // B*NB1
    int*   pidx  = (int*)(pval + B*NB1);        // B*NB1
    int*   ctrl  = pidx + B*NB1;                // B*4

    k_norm<<<A, K, 0, stream>>>(d, dn);
    k_init<<<(B*TP + 255)/256, 256, 0, stream>>>(x, rp, recon);
    k_conv_full<<<dim3((TOUT + 255)/256, A, B), 256, 0, stream>>>(rp, dn, fm);

    for (int it = 0; it < ITERS; it++) {
        k_amax1<<<dim3(NB1, B), 256, 0, stream>>>(fm, pval, pidx);
        k_amax2<<<B, NB1, 0, stream>>>(pval, pidx, ctrl);
        k_update<<<B, K, 0, stream>>>(ctrl, dn, rp, recon);
        if (it + 1 < ITERS)
            k_conv_inc<<<dim3(2, A, B), 256, 0, stream>>>(ctrl, rp, dn, fm);
    }

    k_out<<<(B*T + 255)/256, 256, 0, stream>>>(recon, out);
}

// Round 2
// 1074.713 us; speedup vs baseline: 1.0448x; 1.0448x over previous
//
#include <hip/hip_runtime.h>
#include <hip/hip_bf16.h>
#include <math.h>

#define B    4
#define T    16384
#define A    256
#define K    256
#define PAD  128
#define TP   (T + 2*PAD)      // 16640 padded length
#define TOUT (TP - K + 1)     // 16385 conv output length
#define ITERS 16
#define CHUNK 512
#define NCHUNK 33             // ceil(TOUT/CHUNK); last chunk has 1 elem
#define NSEG  (A*NCHUNK)      // 8448 segments per batch
#define TILE  2048            // conv tile = 4 chunks, TM=8 per thread

// ---------------- atom normalization: dn[a,k] = d[a,k] / (||d[a]|| + 1e-12)
__global__ void k_norm(const float* __restrict__ d, float* __restrict__ dn) {
    int a = blockIdx.x;
    int k = threadIdx.x;          // 256 threads
    float v = d[a*K + k];
    float s = v*v;
    #pragma unroll
    for (int off = 32; off; off >>= 1) s += __shfl_down(s, off);
    __shared__ float ls[4];
    int lane = threadIdx.x & 63, w = threadIdx.x >> 6;
    if (lane == 0) ls[w] = s;
    __syncthreads();
    if (threadIdx.x == 0) ls[0] = ls[0] + ls[1] + ls[2] + ls[3];
    __syncthreads();
    float norm = sqrtf(ls[0]) + 1e-12f;
    dn[a*K + k] = v / norm;
}

// ---------------- init padded residual + zero recon
__global__ void k_init(const float* __restrict__ x, float* __restrict__ rp,
                       float* __restrict__ recon) {
    int i = blockIdx.x * blockDim.x + threadIdx.x;
    if (i >= B*TP) return;
    int b = i / TP, t = i % TP;
    float v = 0.f;
    if (t >= PAD && t < PAD + T) v = x[b*T + (t - PAD)];
    rp[i] = v;
    recon[i] = 0.f;
}

// ---------------- full conv + per-chunk (max,idx): no fm materialization.
// grid (9, A, B), 256 threads; thread computes TM=8 consecutive outputs.
__global__ __launch_bounds__(256) void k_conv_seg(const float* __restrict__ rp,
                                                  const float* __restrict__ dn,
                                                  float* __restrict__ segval,
                                                  int* __restrict__ segidx) {
    __shared__ float s_rp[TILE + K];   // 2304 floats
    __shared__ float s_dn[K];
    int b = blockIdx.z, a = blockIdx.y;
    int t0 = blockIdx.x * TILE;
    int tid = threadIdx.x;
    s_dn[tid] = dn[a*K + tid];
    const float4* rp4 = (const float4*)(rp + (size_t)b*TP);   // TP % 4 == 0
    float4* s4 = (float4*)s_rp;
    for (int i = tid; i < (TILE + K)/4; i += 256) {           // 576 quads
        int g = t0/4 + i;
        float4 v = {0.f,0.f,0.f,0.f};
        if (g*4 < TP) v = rp4[g];
        s4[i] = v;
    }
    __syncthreads();

    int lt = tid * 8;
    float acc[8];
    #pragma unroll
    for (int j = 0; j < 8; j++) acc[j] = 0.f;
    const float4* srp4 = (const float4*)s_rp;
    const float4* sdn4 = (const float4*)s_dn;
    for (int k = 0; k < K; k += 8) {
        float4 d0 = sdn4[k/4], d1 = sdn4[k/4 + 1];
        float dv[8] = {d0.x,d0.y,d0.z,d0.w,d1.x,d1.y,d1.z,d1.w};
        int base = (lt + k) / 4;
        float4 r0 = srp4[base], r1 = srp4[base+1], r2 = srp4[base+2], r3 = srp4[base+3];
        float rr[16] = {r0.x,r0.y,r0.z,r0.w, r1.x,r1.y,r1.z,r1.w,
                        r2.x,r2.y,r2.z,r2.w, r3.x,r3.y,r3.z,r3.w};
        #pragma unroll
        for (int i = 0; i < 8; i++) {
            #pragma unroll
            for (int j = 0; j < 8; j++)
                acc[j] = fmaf(rr[i+j], dv[i], acc[j]);
        }
    }

    // thread-local best (ascending j => lowest idx wins ties via strict >)
    float bv = -INFINITY; int bi = 0x7fffffff;
    #pragma unroll
    for (int j = 0; j < 8; j++) {
        int t = t0 + lt + j;
        if (t < TOUT && acc[j] > bv) { bv = acc[j]; bi = a*TOUT + t; }
    }
    // wave64 reduce; wave w owns chunk blockIdx.x*4 + w (512 consecutive outputs)
    #pragma unroll
    for (int off = 32; off; off >>= 1) {
        float ov = __shfl_down(bv, off);
        int   oi = __shfl_down(bi, off);
        if (ov > bv || (ov == bv && oi < bi)) { bv = ov; bi = oi; }
    }
    int w = tid >> 6;
    int chunk = blockIdx.x*4 + w;
    if ((tid & 63) == 0 && chunk < NCHUNK) {
        segval[((size_t)b*A + a)*NCHUNK + chunk] = bv;
        segidx[((size_t)b*A + a)*NCHUNK + chunk] = bi;
    }
}

// ---------------- pick global best from seg arrays, write ctrl, apply update
__global__ __launch_bounds__(1024) void k_pick_update(const float* __restrict__ segval,
                                                      const int* __restrict__ segidx,
                                                      const float* __restrict__ dn,
                                                      float* __restrict__ rp,
                                                      float* __restrict__ recon,
                                                      int* __restrict__ ctrl) {
    int b = blockIdx.x, tid = threadIdx.x;
    const float* sv = segval + (size_t)b*NSEG;
    const int*   si = segidx + (size_t)b*NSEG;
    float bv = -INFINITY; int bi = 0x7fffffff;
    for (int i = tid; i < NSEG; i += 1024) {
        float v = sv[i]; int ix = si[i];
        if (v > bv || (v == bv && ix < bi)) { bv = v; bi = ix; }
    }
    #pragma unroll
    for (int off = 32; off; off >>= 1) {
        float ov = __shfl_down(bv, off);
        int   oi = __shfl_down(bi, off);
        if (ov > bv || (ov == bv && oi < bi)) { bv = ov; bi = oi; }
    }
    __shared__ float wv[16]; __shared__ int wi[16];
    int lane = tid & 63, w = tid >> 6;
    if (lane == 0) { wv[w] = bv; wi[w] = bi; }
    __syncthreads();
    __shared__ float finv; __shared__ int fini;
    if (tid == 0) {
        for (int j = 1; j < 16; j++)
            if (wv[j] > bv || (wv[j] == bv && wi[j] < bi)) { bv = wv[j]; bi = wi[j]; }
        finv = bv; fini = bi;
        ctrl[b*4 + 0] = bi / TOUT;
        ctrl[b*4 + 1] = bi % TOUT;
        ((float*)ctrl)[b*4 + 2] = bv;
    }
    __syncthreads();
    float val = finv; int idx = fini;
    int atom = idx / TOUT, pos = idx % TOUT;
    if (tid < K) {
        float av = dn[atom*K + tid] * val;
        rp[(size_t)b*TP + pos + tid]    -= av;
        recon[(size_t)b*TP + pos + tid] += av;
    }
}

// ---------------- recompute the two chunks overlapping the changed window.
// grid (A, B), 256 threads, TM=4 over 1024 positions starting at c_lo*512.
// Recomputes both chunks entirely from rp (bitwise-same fmaf chain as k_conv_seg).
__global__ __launch_bounds__(256) void k_incseg(const int* __restrict__ ctrl,
                                                const float* __restrict__ rp,
                                                const float* __restrict__ dn,
                                                float* __restrict__ segval,
                                                int* __restrict__ segidx) {
    __shared__ float s_rp[2*CHUNK + K];   // 1280 floats
    __shared__ float s_dn[K];
    int a = blockIdx.x, b = blockIdx.y, tid = threadIdx.x;
    int pos = ctrl[b*4 + 1];
    int lo = pos - (K-1); if (lo < 0) lo = 0;
    int c_lo = lo >> 9;                   // window spans chunks [c_lo, c_lo+1]
    int tbase = c_lo * CHUNK;
    s_dn[tid] = dn[a*K + tid];
    const float4* rp4 = (const float4*)(rp + (size_t)b*TP);
    float4* s4 = (float4*)s_rp;
    for (int i = tid; i < (2*CHUNK + K)/4; i += 256) {   // 320 quads
        int g = tbase/4 + i;
        float4 v = {0.f,0.f,0.f,0.f};
        if (g*4 < TP) v = rp4[g];
        s4[i] = v;
    }
    __syncthreads();

    int lt = tid * 4;
    float acc[4] = {0.f,0.f,0.f,0.f};
    const float4* srp4 = (const float4*)s_rp;
    const float4* sdn4 = (const float4*)s_dn;
    for (int k = 0; k < K; k += 8) {
        float4 d0 = sdn4[k/4], d1 = sdn4[k/4 + 1];
        float dv[8] = {d0.x,d0.y,d0.z,d0.w,d1.x,d1.y,d1.z,d1.w};
        int base = (lt + k) / 4;
        float4 r0 = srp4[base], r1 = srp4[base+1], r2 = srp4[base+2];
        float rr[12] = {r0.x,r0.y,r0.z,r0.w, r1.x,r1.y,r1.z,r1.w,
                        r2.x,r2.y,r2.z,r2.w};
        #pragma unroll
        for (int i = 0; i < 8; i++) {
            #pragma unroll
            for (int j = 0; j < 4; j++)
                acc[j] = fmaf(rr[i+j], dv[i], acc[j]);
        }
    }

    float bv = -INFINITY; int bi = 0x7fffffff;
    #pragma unroll
    for (int j = 0; j < 4; j++) {
        int t = tbase + lt + j;
        if (t < TOUT && acc[j] > bv) { bv = acc[j]; bi = a*TOUT + t; }
    }
    #pragma unroll
    for (int off = 32; off; off >>= 1) {
        float ov = __shfl_down(bv, off);
        int   oi = __shfl_down(bi, off);
        if (ov > bv || (ov == bv && oi < bi)) { bv = ov; bi = oi; }
    }
    // waves {0,1} -> chunk c_lo ; waves {2,3} -> chunk c_lo+1
    __shared__ float wv[4]; __shared__ int wi[4];
    if ((tid & 63) == 0) { wv[tid >> 6] = bv; wi[tid >> 6] = bi; }
    __syncthreads();
    if (tid < 2) {
        float v0 = wv[2*tid]; int i0 = wi[2*tid];
        float v1 = wv[2*tid + 1]; int i1 = wi[2*tid + 1];
        if (v1 > v0 || (v1 == v0 && i1 < i0)) { v0 = v1; i0 = i1; }
        int chunk = c_lo + tid;
        if (chunk < NCHUNK) {
            segval[((size_t)b*A + a)*NCHUNK + chunk] = v0;
            segidx[((size_t)b*A + a)*NCHUNK + chunk] = i0;
        }
    }
}

// ---------------- crop recon padding into output
__global__ void k_out(const float* __restrict__ recon, float* __restrict__ out) {
    int i = blockIdx.x * blockDim.x + threadIdx.x;
    if (i >= B*T) return;
    int b = i / T, t = i % T;
    out[i] = recon[(size_t)b*TP + PAD + t];
}

extern "C" void kernel_launch(void* const* d_in, const int* in_sizes, int n_in,
                              void* d_out, int out_size, void* d_ws, size_t ws_size,
                              hipStream_t stream) {
    const float* x = (const float*)d_in[0];
    const float* d = (const float*)d_in[1];
    float* out = (float*)d_out;

    float* ws     = (float*)d_ws;
    float* dn     = ws;                          // A*K      = 65536
    float* rp     = dn + (size_t)A*K;            // B*TP     = 66560
    float* recon  = rp + (size_t)B*TP;           // B*TP     = 66560
    float* segval = recon + (size_t)B*TP;        // B*NSEG   = 33792
    int*   segidx = (int*)(segval + (size_t)B*NSEG);   // B*NSEG
    int*   ctrl   = segidx + (size_t)B*NSEG;     // B*4

    k_norm<<<A, K, 0, stream>>>(d, dn);
    k_init<<<(B*TP + 255)/256, 256, 0, stream>>>(x, rp, recon);
    k_conv_seg<<<dim3((TOUT + TILE - 1)/TILE, A, B), 256, 0, stream>>>(rp, dn, segval, segidx);

    for (int it = 0; it < ITERS; it++) {
        k_pick_update<<<B, 1024, 0, stream>>>(segval, segidx, dn, rp, recon, ctrl);
        if (it + 1 < ITERS)
            k_incseg<<<dim3(A, B), 256, 0, stream>>>(ctrl, rp, dn, segval, segidx);
    }

    k_out<<<(B*T + 255)/256, 256, 0, stream>>>(recon, out);
}

// Round 3
// 716.131 us; speedup vs baseline: 1.5679x; 1.5007x over previous
//
#include <hip/hip_runtime.h>
#include <hip/hip_bf16.h>
#include <math.h>

#define B    4
#define T    16384
#define A    256
#define K    256
#define PAD  128
#define TP   (T + 2*PAD)      // 16640 padded length
#define TOUT (TP - K + 1)     // 16385 conv output length
#define ITERS 16
#define CHUNK 512
#define NCHUNK 33             // ceil(TOUT/CHUNK); last chunk has 1 elem
#define NSEG  (A*NCHUNK)      // 8448 segments per batch
#define TILE  2048            // conv tile = 4 chunks

// ---------------- atom normalization: dn[a,k] = d[a,k] / (||d[a]|| + 1e-12)
__global__ void k_norm(const float* __restrict__ d, float* __restrict__ dn) {
    int a = blockIdx.x;
    int k = threadIdx.x;
    float v = d[a*K + k];
    float s = v*v;
    #pragma unroll
    for (int off = 32; off; off >>= 1) s += __shfl_down(s, off);
    __shared__ float ls[4];
    int lane = threadIdx.x & 63, w = threadIdx.x >> 6;
    if (lane == 0) ls[w] = s;
    __syncthreads();
    if (threadIdx.x == 0) ls[0] = ls[0] + ls[1] + ls[2] + ls[3];
    __syncthreads();
    float norm = sqrtf(ls[0]) + 1e-12f;
    dn[a*K + k] = v / norm;
}

// ---------------- init padded residual + zero recon
__global__ void k_init(const float* __restrict__ x, float* __restrict__ rp,
                       float* __restrict__ recon) {
    int i = blockIdx.x * blockDim.x + threadIdx.x;
    if (i >= B*TP) return;
    int b = i / TP, t = i % TP;
    float v = 0.f;
    if (t >= PAD && t < PAD + T) v = x[b*T + (t - PAD)];
    rp[i] = v;
    recon[i] = 0.f;
}

__device__ __forceinline__ void wave_amax(float& bv, int& bi) {
    #pragma unroll
    for (int off = 32; off; off >>= 1) {
        float ov = __shfl_down(bv, off);
        int   oi = __shfl_down(bi, off);
        if (ov > bv || (ov == bv && oi < bi)) { bv = ov; bi = oi; }
    }
}

// ---------------- full conv + per-chunk (max,idx). grid (9, A, B), 256 thr.
// Thread handles outputs t0+tid*4+j and t0+1024+tid*4+j (conflict-free b128 LDS).
__global__ __launch_bounds__(256) void k_conv_seg(const float* __restrict__ rp,
                                                  const float* __restrict__ dn,
                                                  float* __restrict__ segval,
                                                  int* __restrict__ segidx) {
    __shared__ float s_rp[TILE + K + 16];   // +16 pad for harmless prefetch
    __shared__ float s_dn[K];
    int b = blockIdx.z, a = blockIdx.y;
    int t0 = blockIdx.x * TILE;
    int tid = threadIdx.x;
    s_dn[tid] = dn[a*K + tid];
    const float4* rp4 = (const float4*)(rp + (size_t)b*TP);
    float4* s4 = (float4*)s_rp;
    for (int i = tid; i < (TILE + K)/4; i += 256) {          // 576 quads
        int g = t0/4 + i;
        float4 v = {0.f,0.f,0.f,0.f};
        if (g*4 < TP) v = rp4[g];
        s4[i] = v;
    }
    __syncthreads();

    const float4* srp4 = (const float4*)s_rp;
    const float4* sdn4 = (const float4*)s_dn;
    float acc0[4] = {0,0,0,0}, acc1[4] = {0,0,0,0};
    float4 a0 = srp4[tid],       a1 = srp4[tid + 1];
    float4 b0 = srp4[tid + 256], b1 = srp4[tid + 257];
    for (int k = 0; k < K; k += 8) {
        float4 dq0 = sdn4[k/4], dq1 = sdn4[k/4 + 1];
        float4 a2 = srp4[tid + k/4 + 2];
        float4 a3 = srp4[tid + k/4 + 3];
        float4 b2 = srp4[tid + 256 + k/4 + 2];
        float4 b3 = srp4[tid + 256 + k/4 + 3];
        float dv[8] = {dq0.x,dq0.y,dq0.z,dq0.w, dq1.x,dq1.y,dq1.z,dq1.w};
        float ra[12] = {a0.x,a0.y,a0.z,a0.w, a1.x,a1.y,a1.z,a1.w, a2.x,a2.y,a2.z,a2.w};
        float rb[12] = {b0.x,b0.y,b0.z,b0.w, b1.x,b1.y,b1.z,b1.w, b2.x,b2.y,b2.z,b2.w};
        #pragma unroll
        for (int i = 0; i < 8; i++) {
            #pragma unroll
            for (int j = 0; j < 4; j++) {
                acc0[j] = fmaf(ra[i+j], dv[i], acc0[j]);
                acc1[j] = fmaf(rb[i+j], dv[i], acc1[j]);
            }
        }
        a0 = a2; a1 = a3; b0 = b2; b1 = b3;
    }

    int lt = tid * 4;
    float bv0 = -INFINITY; int bi0 = 0x7fffffff;
    #pragma unroll
    for (int j = 0; j < 4; j++) {
        int t = t0 + lt + j;
        if (t < TOUT && acc0[j] > bv0) { bv0 = acc0[j]; bi0 = a*TOUT + t; }
    }
    float bv1 = -INFINITY; int bi1 = 0x7fffffff;
    #pragma unroll
    for (int j = 0; j < 4; j++) {
        int t = t0 + 1024 + lt + j;
        if (t < TOUT && acc1[j] > bv1) { bv1 = acc1[j]; bi1 = a*TOUT + t; }
    }
    wave_amax(bv0, bi0);
    wave_amax(bv1, bi1);
    // partial p = group*4 + wave covers outputs [t0 + group*1024 + wave*256, +256)
    __shared__ float sv[8]; __shared__ int si[8];
    int w = tid >> 6;
    if ((tid & 63) == 0) { sv[w] = bv0; si[w] = bi0; sv[4+w] = bv1; si[4+w] = bi1; }
    __syncthreads();
    if (tid < 4) {        // chunk (within tile) c <- partials 2c, 2c+1
        float v0 = sv[2*tid];   int i0 = si[2*tid];
        float v1 = sv[2*tid+1]; int i1 = si[2*tid+1];
        if (v1 > v0 || (v1 == v0 && i1 < i0)) { v0 = v1; i0 = i1; }
        int chunk = blockIdx.x*4 + tid;
        if (chunk < NCHUNK) {
            segval[((size_t)b*A + a)*NCHUNK + chunk] = v0;
            segidx[((size_t)b*A + a)*NCHUNK + chunk] = i0;
        }
    }
}

// ---------------- fused iteration: redundant pick + local update + recompute
// grid (A, B), 256 threads. rp double-buffered; a==0 writes rp_out & recon.
__global__ __launch_bounds__(256) void k_iter(const float* __restrict__ segval,
                                              int* __restrict__ segidx,
                                              const float* __restrict__ dn,
                                              const float* __restrict__ rp_in,
                                              float* __restrict__ rp_out,
                                              float* __restrict__ recon,
                                              float* __restrict__ segval_w) {
    __shared__ float s_rp[2*CHUNK + K + 16];
    __shared__ float s_dn_a[K];
    __shared__ float s_dn_sel[K];
    __shared__ float wv[4]; __shared__ int wi[4];
    __shared__ float s_val; __shared__ int s_idx;
    int a = blockIdx.x, b = blockIdx.y, tid = threadIdx.x;

    // --- pick (redundant, deterministic across blocks of same b)
    const float* sv = segval + (size_t)b*NSEG;
    const int*   si = segidx + (size_t)b*NSEG;
    float bv = -INFINITY; int bi = 0x7fffffff;
    for (int i = tid; i < NSEG; i += 256) {
        float v = sv[i]; int ix = si[i];
        if (v > bv || (v == bv && ix < bi)) { bv = v; bi = ix; }
    }
    wave_amax(bv, bi);
    int lane = tid & 63, w = tid >> 6;
    if (lane == 0) { wv[w] = bv; wi[w] = bi; }
    __syncthreads();
    if (tid == 0) {
        for (int j = 1; j < 4; j++)
            if (wv[j] > bv || (wv[j] == bv && wi[j] < bi)) { bv = wv[j]; bi = wi[j]; }
        s_val = bv; s_idx = bi;
    }
    __syncthreads();
    float val = s_val; int idx = s_idx;
    int atom = idx / TOUT, pos = idx % TOUT;

    // --- stage tile + atoms, apply update in LDS
    int lo = pos - (K-1); if (lo < 0) lo = 0;
    int c_lo = lo >> 9;
    int tbase = c_lo * CHUNK;
    s_dn_a[tid]   = dn[a*K + tid];
    s_dn_sel[tid] = dn[atom*K + tid];
    const float4* rp4 = (const float4*)(rp_in + (size_t)b*TP);
    float4* s4 = (float4*)s_rp;
    for (int i = tid; i < (2*CHUNK + K)/4; i += 256) {   // 320 quads
        int g = tbase/4 + i;
        float4 v = {0.f,0.f,0.f,0.f};
        if (g*4 < TP) v = rp4[g];
        s4[i] = v;
    }
    __syncthreads();
    {   // rp changed region is [pos, pos+K)
        int local = pos + tid - tbase;
        if (local >= 0 && local < 2*CHUNK + K) s_rp[local] -= val * s_dn_sel[tid];
    }
    __syncthreads();

    // --- designated writer: rp_out (whole row, updated) and recon
    if (a == 0) {
        for (int i = tid; i < TP; i += 256) {
            float v = rp_in[(size_t)b*TP + i];
            int o = i - pos;
            if (o >= 0 && o < K) v -= val * s_dn_sel[o];
            rp_out[(size_t)b*TP + i] = v;
        }
        recon[(size_t)b*TP + pos + tid] += val * s_dn_sel[tid];
    }

    // --- recompute 1024 outputs (chunks c_lo, c_lo+1), TM=4, conflict-free
    const float4* srp4 = (const float4*)s_rp;
    const float4* sdn4 = (const float4*)s_dn_a;
    float acc[4] = {0,0,0,0};
    float4 w0 = srp4[tid], w1 = srp4[tid + 1];
    for (int k = 0; k < K; k += 8) {
        float4 dq0 = sdn4[k/4], dq1 = sdn4[k/4 + 1];
        float4 w2 = srp4[tid + k/4 + 2];
        float4 w3 = srp4[tid + k/4 + 3];
        float dv[8] = {dq0.x,dq0.y,dq0.z,dq0.w, dq1.x,dq1.y,dq1.z,dq1.w};
        float rr[12] = {w0.x,w0.y,w0.z,w0.w, w1.x,w1.y,w1.z,w1.w, w2.x,w2.y,w2.z,w2.w};
        #pragma unroll
        for (int i = 0; i < 8; i++) {
            #pragma unroll
            for (int j = 0; j < 4; j++)
                acc[j] = fmaf(rr[i+j], dv[i], acc[j]);
        }
        w0 = w2; w1 = w3;
    }
    int lt = tid * 4;
    float cbv = -INFINITY; int cbi = 0x7fffffff;
    #pragma unroll
    for (int j = 0; j < 4; j++) {
        int t = tbase + lt + j;
        if (t < TOUT && acc[j] > cbv) { cbv = acc[j]; cbi = a*TOUT + t; }
    }
    wave_amax(cbv, cbi);
    __shared__ float cv[4]; __shared__ int ci[4];
    if (lane == 0) { cv[w] = cbv; ci[w] = cbi; }
    __syncthreads();
    if (tid < 2) {   // chunk c_lo+tid <- waves 2*tid, 2*tid+1
        float v0 = cv[2*tid];   int i0 = ci[2*tid];
        float v1 = cv[2*tid+1]; int i1 = ci[2*tid+1];
        if (v1 > v0 || (v1 == v0 && i1 < i0)) { v0 = v1; i0 = i1; }
        int chunk = c_lo + tid;
        if (chunk < NCHUNK) {
            segval_w[((size_t)b*A + a)*NCHUNK + chunk] = v0;
            segidx[((size_t)b*A + a)*NCHUNK + chunk] = i0;
        }
    }
}

// ---------------- final pick: update recon only. grid (B), 256 threads.
__global__ __launch_bounds__(256) void k_pick_final(const float* __restrict__ segval,
                                                    const int* __restrict__ segidx,
                                                    const float* __restrict__ dn,
                                                    float* __restrict__ recon) {
    __shared__ float wv[4]; __shared__ int wi[4];
    __shared__ float s_val; __shared__ int s_idx;
    int b = blockIdx.x, tid = threadIdx.x;
    const float* sv = segval + (size_t)b*NSEG;
    const int*   si = segidx + (size_t)b*NSEG;
    float bv = -INFINITY; int bi = 0x7fffffff;
    for (int i = tid; i < NSEG; i += 256) {
        float v = sv[i]; int ix = si[i];
        if (v > bv || (v == bv && ix < bi)) { bv = v; bi = ix; }
    }
    wave_amax(bv, bi);
    int lane = tid & 63, w = tid >> 6;
    if (lane == 0) { wv[w] = bv; wi[w] = bi; }
    __syncthreads();
    if (tid == 0) {
        for (int j = 1; j < 4; j++)
            if (wv[j] > bv || (wv[j] == bv && wi[j] < bi)) { bv = wv[j]; bi = wi[j]; }
        s_val = bv; s_idx = bi;
    }
    __syncthreads();
    float val = s_val; int idx = s_idx;
    int atom = idx / TOUT, pos = idx % TOUT;
    recon[(size_t)b*TP + pos + tid] += val * dn[atom*K + tid];
}

// ---------------- crop recon padding into output
__global__ void k_out(const float* __restrict__ recon, float* __restrict__ out) {
    int i = blockIdx.x * blockDim.x + threadIdx.x;
    if (i >= B*T) return;
    int b = i / T, t = i % T;
    out[i] = recon[(size_t)b*TP + PAD + t];
}

extern "C" void kernel_launch(void* const* d_in, const int* in_sizes, int n_in,
                              void* d_out, int out_size, void* d_ws, size_t ws_size,
                              hipStream_t stream) {
    const float* x = (const float*)d_in[0];
    const float* d = (const float*)d_in[1];
    float* out = (float*)d_out;

    float* ws     = (float*)d_ws;
    float* dn     = ws;                                 // A*K
    float* rp0    = dn  + (size_t)A*K;                  // B*TP
    float* rp1    = rp0 + (size_t)B*TP;                 // B*TP
    float* recon  = rp1 + (size_t)B*TP;                 // B*TP
    float* segval = recon + (size_t)B*TP;               // B*NSEG
    int*   segidx = (int*)(segval + (size_t)B*NSEG);    // B*NSEG

    k_norm<<<A, K, 0, stream>>>(d, dn);
    k_init<<<(B*TP + 255)/256, 256, 0, stream>>>(x, rp0, recon);
    k_conv_seg<<<dim3((TOUT + TILE - 1)/TILE, A, B), 256, 0, stream>>>(rp0, dn, segval, segidx);

    float* bufs[2] = {rp0, rp1};
    for (int it = 0; it < ITERS - 1; it++) {
        k_iter<<<dim3(A, B), 256, 0, stream>>>(segval, segidx, dn,
                                               bufs[it & 1], bufs[(it + 1) & 1],
                                               recon, segval);
    }
    k_pick_final<<<B, 256, 0, stream>>>(segval, segidx, dn, recon);
    k_out<<<(B*T + 255)/256, 256, 0, stream>>>(recon, out);
}